// Round 1
// baseline (190.936 us; speedup 1.0000x reference)
//
#include <hip/hip_runtime.h>
#include <hip/hip_bf16.h>

#define CIN 8
#define IMG 224
#define PS 16
#define HP 14
#define D_ 768
#define HID 128
#define MPT 196      // Hp*Wp
#define NBATCH 32
#define K_ 256       // PS*PS
#define WSIZE 196608 // D_*K_
#define NJ 197376    // WSIZE + D_

typedef __bf16 bf16x8 __attribute__((ext_vector_type(8)));
typedef float f32x4 __attribute__((ext_vector_type(4)));

static __device__ __forceinline__ ushort f2bf(float f) {
  union { float f; unsigned int u; } x; x.f = f;
  unsigned int r = x.u + 0x7fffu + ((x.u >> 16) & 1u);
  return (ushort)(r >> 16);
}

// ---------- k1: h = relu(ce @ fc1_w + b1)  -> (8,128) fp32
__global__ void k1_fc1(const float* __restrict__ ce, const float* __restrict__ w1,
                       const float* __restrict__ b1, float* __restrict__ h) {
  int c = blockIdx.x;
  int i = threadIdx.x;
  const float* cev = ce + c * D_;
  float acc = b1[i];
#pragma unroll 4
  for (int d = 0; d < D_; ++d)
    acc = fmaf(cev[d], w1[d * HID + i], acc);
  h[c * HID + i] = fmaxf(acc, 0.0f);
}

// ---------- k2: y = tanh(h @ fc2_w + b2); scatter wts(bf16, [c][d*256+k]) + bias(fp32)
__global__ __launch_bounds__(256) void k2_fc2(
    const float* __restrict__ h, const float* __restrict__ w2,
    const float* __restrict__ b2, ushort* __restrict__ wbf,
    float* __restrict__ biasOut) {
  __shared__ float hs[CIN * HID];
  int t = threadIdx.x;
  for (int o = t; o < CIN * HID; o += 256) hs[o] = h[o];
  __syncthreads();
  int j0 = blockIdx.x * 1024 + t * 4;
  if (j0 >= NJ) return;

  float acc[CIN][4];
#pragma unroll
  for (int c = 0; c < CIN; ++c)
#pragma unroll
    for (int q = 0; q < 4; ++q) acc[c][q] = 0.0f;

  for (int i = 0; i < HID; ++i) {
    float4 w = *(const float4*)(w2 + (size_t)i * NJ + j0);
#pragma unroll
    for (int c = 0; c < CIN; ++c) {
      float hv = hs[c * HID + i];
      acc[c][0] = fmaf(hv, w.x, acc[c][0]);
      acc[c][1] = fmaf(hv, w.y, acc[c][1]);
      acc[c][2] = fmaf(hv, w.z, acc[c][2]);
      acc[c][3] = fmaf(hv, w.w, acc[c][3]);
    }
  }
  float4 bb = *(const float4*)(b2 + j0);
  if (j0 < WSIZE) {
#pragma unroll
    for (int c = 0; c < CIN; ++c) {
      ushort4 pk;
      pk.x = f2bf(tanhf(acc[c][0] + bb.x));
      pk.y = f2bf(tanhf(acc[c][1] + bb.y));
      pk.z = f2bf(tanhf(acc[c][2] + bb.z));
      pk.w = f2bf(tanhf(acc[c][3] + bb.w));
      *(ushort4*)(wbf + (size_t)c * WSIZE + j0) = pk;
    }
  } else {
#pragma unroll
    for (int c = 0; c < CIN; ++c) {
      float4 o;
      o.x = tanhf(acc[c][0] + bb.x);
      o.y = tanhf(acc[c][1] + bb.y);
      o.z = tanhf(acc[c][2] + bb.z);
      o.w = tanhf(acc[c][3] + bb.w);
      *(float4*)(biasOut + c * D_ + (j0 - WSIZE)) = o;
    }
  }
}

// ---------- k3: per-channel GEMM  out[b,c,hw,d] = sum_k patch(x) * wts + bias
#define BK 64
#define LDK 72  // +8 bf16 pad: row stride 144 B -> 4-bank rotation per row

__global__ __launch_bounds__(256, 2) void k3_gemm(
    const float* __restrict__ x, const ushort* __restrict__ wbf,
    const float* __restrict__ bias, float* __restrict__ out) {
  __shared__ ushort As[128 * LDK];
  __shared__ ushort Bs[128 * LDK];

  int bid = blockIdx.x;
  int c = bid & 7;              // channel == XCD (bid % 8): weights L2-resident per XCD
  int rem = bid >> 3;           // 0..293
  int mt = rem / 6;
  int nt = rem - mt * 6;        // 6 consecutive siblings share the A-tile on one XCD
  int m0 = mt * 128, n0 = nt * 128;

  int t = threadIdx.x;
  int lane = t & 63;
  int w = t >> 6;
  int wr = w >> 1, wc = w & 1;

  // A-staging source: this thread's patch row (hoisted; constant across K-steps)
  int m_l = t & 127;
  int pgrp = t >> 7;            // 0 or 1
  int m = m0 + m_l;
  int b = m / MPT;
  int hw = m - b * MPT;
  int hp = hw / HP;
  int wp = hw - hp * HP;
  const float* xrow0 = x + (((size_t)(b * CIN + c) * IMG + hp * PS) * IMG + wp * PS);
  const ushort* wsrc = wbf + (size_t)c * WSIZE + (size_t)n0 * K_;

  f32x4 acc[4][4] = {};

  for (int ks = 0; ks < 4; ++ks) {
    __syncthreads();
    // ---- stage A: 128 rows x 64 k (p in [ks*4, ks*4+4)), fp32 -> bf16
#pragma unroll
    for (int s = 0; s < 2; ++s) {
      int pl = s * 2 + pgrp;    // 0..3
      const float* src = xrow0 + (ks * 4 + pl) * IMG;
      float4 f0 = *(const float4*)(src + 0);
      float4 f1 = *(const float4*)(src + 4);
      float4 f2 = *(const float4*)(src + 8);
      float4 f3 = *(const float4*)(src + 12);
      union { ushort u[16]; uint4 v[2]; } pk;
      pk.u[0]  = f2bf(f0.x); pk.u[1]  = f2bf(f0.y); pk.u[2]  = f2bf(f0.z); pk.u[3]  = f2bf(f0.w);
      pk.u[4]  = f2bf(f1.x); pk.u[5]  = f2bf(f1.y); pk.u[6]  = f2bf(f1.z); pk.u[7]  = f2bf(f1.w);
      pk.u[8]  = f2bf(f2.x); pk.u[9]  = f2bf(f2.y); pk.u[10] = f2bf(f2.z); pk.u[11] = f2bf(f2.w);
      pk.u[12] = f2bf(f3.x); pk.u[13] = f2bf(f3.y); pk.u[14] = f2bf(f3.z); pk.u[15] = f2bf(f3.w);
      uint4* dst = (uint4*)&As[m_l * LDK + pl * 16];
      dst[0] = pk.v[0];
      dst[1] = pk.v[1];
    }
    // ---- stage B: 128 N-rows x 64 k, bf16 copy (L2-resident)
#pragma unroll
    for (int i2 = 0; i2 < 4; ++i2) {
      int cg = t + i2 * 256;
      int n_l = cg >> 3, part = cg & 7;
      *(uint4*)&Bs[n_l * LDK + part * 8] =
          *(const uint4*)(wsrc + n_l * K_ + ks * BK + part * 8);
    }
    __syncthreads();
    // ---- compute: 2 kk-steps of 32, 4x4 fragments per wave
#pragma unroll
    for (int kk = 0; kk < BK; kk += 32) {
      bf16x8 af[4], bfr[4];
#pragma unroll
      for (int mi = 0; mi < 4; ++mi)
        af[mi] = *(const bf16x8*)&As[(wr * 64 + mi * 16 + (lane & 15)) * LDK + kk + (lane >> 4) * 8];
#pragma unroll
      for (int ni = 0; ni < 4; ++ni)
        bfr[ni] = *(const bf16x8*)&Bs[(wc * 64 + ni * 16 + (lane & 15)) * LDK + kk + (lane >> 4) * 8];
#pragma unroll
      for (int mi = 0; mi < 4; ++mi)
#pragma unroll
        for (int ni = 0; ni < 4; ++ni)
          acc[mi][ni] = __builtin_amdgcn_mfma_f32_16x16x32_bf16(af[mi], bfr[ni], acc[mi][ni], 0, 0, 0);
    }
  }

  // ---- epilogue: + bias, fp32 store.  C/D: col = lane&15, row = (lane>>4)*4 + reg
  int col_l = lane & 15;
  int rowg = lane >> 4;
  float bv[4];
#pragma unroll
  for (int ni = 0; ni < 4; ++ni)
    bv[ni] = bias[c * D_ + n0 + wc * 64 + ni * 16 + col_l];
#pragma unroll
  for (int mi = 0; mi < 4; ++mi) {
#pragma unroll
    for (int r = 0; r < 4; ++r) {
      int mrow = m0 + wr * 64 + mi * 16 + rowg * 4 + r;
      int b2 = mrow / MPT;
      int hw2 = mrow - b2 * MPT;
      float* op = out + ((size_t)b2 * (CIN * MPT) + c * MPT + hw2) * D_ + n0 + wc * 64 + col_l;
#pragma unroll
      for (int ni = 0; ni < 4; ++ni)
        op[ni * 16] = acc[mi][ni][r] + bv[ni];
    }
  }
}

extern "C" void kernel_launch(void* const* d_in, const int* in_sizes, int n_in,
                              void* d_out, int out_size, void* d_ws, size_t ws_size,
                              hipStream_t stream) {
  const float* x  = (const float*)d_in[0];
  // d_in[1] (channels) is unused by the reference computation
  const float* ce = (const float*)d_in[2];
  const float* w1 = (const float*)d_in[3];
  const float* b1 = (const float*)d_in[4];
  const float* w2 = (const float*)d_in[5];
  const float* b2 = (const float*)d_in[6];
  float* out = (float*)d_out;

  char* ws = (char*)d_ws;
  float*  h       = (float*)ws;                    // 8*128*4    = 4096 B
  float*  biasOut = (float*)(ws + 4096);           // 8*768*4    = 24576 B
  ushort* wbf     = (ushort*)(ws + 4096 + 24576);  // 8*196608*2 = 3145728 B

  k1_fc1<<<dim3(CIN), dim3(HID), 0, stream>>>(ce, w1, b1, h);
  k2_fc2<<<dim3((NJ + 1023) / 1024), dim3(256), 0, stream>>>(h, w2, b2, wbf, biasOut);
  k3_gemm<<<dim3(8 * 49 * 6), dim3(256), 0, stream>>>(x, wbf, biasOut, out);
}

// Round 2
// 95.595 us; speedup vs baseline: 1.9973x; 1.9973x over previous
//
#include <hip/hip_runtime.h>
#include <hip/hip_bf16.h>

#define CIN 8
#define IMG 224
#define PS 16
#define HP 14
#define D_ 768
#define HID 128
#define MPT 196      // Hp*Wp
#define K_ 256       // PS*PS
#define WSIZE 196608 // D_*K_
#define NJ 197376    // WSIZE + D_
#define XN (32 * CIN * IMG * IMG)  // 12,845,056 x elements

typedef __bf16 bf16x8 __attribute__((ext_vector_type(8)));
typedef float f32x4 __attribute__((ext_vector_type(4)));

static __device__ __forceinline__ ushort f2bf(float f) {
  union { float f; unsigned int u; } x; x.f = f;
  unsigned int r = x.u + 0x7fffu + ((x.u >> 16) & 1u);
  return (ushort)(r >> 16);
}

// async global -> LDS, 16B per lane. LDS base must be wave-uniform; global addr per-lane.
static __device__ __forceinline__ void gload16(const void* g, void* l) {
  __builtin_amdgcn_global_load_lds(
      (const __attribute__((address_space(1))) unsigned int*)(uintptr_t)g,
      (__attribute__((address_space(3))) unsigned int*)(uintptr_t)l, 16, 0, 0);
}

// ---------- k1: ht[i][c] = relu(ce @ fc1_w + b1), 4-way K-split per block
__global__ __launch_bounds__(512) void k1_fc1(const float* __restrict__ ce,
                                              const float* __restrict__ w1,
                                              const float* __restrict__ b1,
                                              float* __restrict__ ht) {
  __shared__ float sh[3][HID];
  int c = blockIdx.x;
  int t = threadIdx.x;
  int i = t & 127, ksp = t >> 7;
  const float* cev = ce + c * D_ + ksp * 192;
  const float* wp = w1 + (size_t)(ksp * 192) * HID + i;
  float acc = 0.f;
#pragma unroll 8
  for (int d = 0; d < 192; ++d) acc = fmaf(cev[d], wp[(size_t)d * HID], acc);
  if (ksp) sh[ksp - 1][i] = acc;
  __syncthreads();
  if (ksp == 0) {
    float s = b1[i] + acc + sh[0][i] + sh[1][i] + sh[2][i];
    ht[i * CIN + c] = fmaxf(s, 0.f);
  }
}

// ---------- k2x: fused {y = tanh(h@fc2_w + b2) scatter} + {x fp32 -> bf16 convert}
// col blocks [0, nCol): 1 column/thread. conv blocks [nCol, gridDim): grid-stride x convert.
__global__ __launch_bounds__(256) void k2_fused(
    const float* __restrict__ ht, const float* __restrict__ w2,
    const float* __restrict__ b2, const float* __restrict__ x,
    ushort* __restrict__ wbf, float* __restrict__ biasOut,
    ushort* __restrict__ xbf, int nCol) {
  int bid = blockIdx.x;
  int t = threadIdx.x;
  if (bid >= nCol) {
    // ---- x -> bf16 (8 elements / thread / iter)
    int u = (bid - nCol) * 256 + t;
    int stride = (gridDim.x - nCol) * 256;
    const float4* xv = (const float4*)x;
    for (int v = u; v < XN / 8; v += stride) {
      float4 f0 = xv[v * 2], f1 = xv[v * 2 + 1];
      union { ushort s[8]; uint4 q; } pk;
      pk.s[0] = f2bf(f0.x); pk.s[1] = f2bf(f0.y); pk.s[2] = f2bf(f0.z); pk.s[3] = f2bf(f0.w);
      pk.s[4] = f2bf(f1.x); pk.s[5] = f2bf(f1.y); pk.s[6] = f2bf(f1.z); pk.s[7] = f2bf(f1.w);
      *(uint4*)(xbf + (size_t)v * 8) = pk.q;
    }
    return;
  }
  int j = bid * 256 + t;
  const float* wp = w2 + j;
  const float4* ht4 = (const float4*)ht;  // ht[i][0..8): uniform -> scalar loads
  float4 a0 = {0, 0, 0, 0}, a1 = {0, 0, 0, 0};
#pragma unroll 8
  for (int i = 0; i < HID; ++i) {
    float wv = wp[(size_t)i * NJ];
    float4 hA = ht4[i * 2], hB = ht4[i * 2 + 1];
    a0.x = fmaf(hA.x, wv, a0.x); a0.y = fmaf(hA.y, wv, a0.y);
    a0.z = fmaf(hA.z, wv, a0.z); a0.w = fmaf(hA.w, wv, a0.w);
    a1.x = fmaf(hB.x, wv, a1.x); a1.y = fmaf(hB.y, wv, a1.y);
    a1.z = fmaf(hB.z, wv, a1.z); a1.w = fmaf(hB.w, wv, a1.w);
  }
  float bb = b2[j];
  if (j < WSIZE) {
    wbf[(size_t)0 * WSIZE + j] = f2bf(tanhf(a0.x + bb));
    wbf[(size_t)1 * WSIZE + j] = f2bf(tanhf(a0.y + bb));
    wbf[(size_t)2 * WSIZE + j] = f2bf(tanhf(a0.z + bb));
    wbf[(size_t)3 * WSIZE + j] = f2bf(tanhf(a0.w + bb));
    wbf[(size_t)4 * WSIZE + j] = f2bf(tanhf(a1.x + bb));
    wbf[(size_t)5 * WSIZE + j] = f2bf(tanhf(a1.y + bb));
    wbf[(size_t)6 * WSIZE + j] = f2bf(tanhf(a1.z + bb));
    wbf[(size_t)7 * WSIZE + j] = f2bf(tanhf(a1.w + bb));
  } else {
    int jb = j - WSIZE;
    biasOut[0 * D_ + jb] = tanhf(a0.x + bb);
    biasOut[1 * D_ + jb] = tanhf(a0.y + bb);
    biasOut[2 * D_ + jb] = tanhf(a0.z + bb);
    biasOut[3 * D_ + jb] = tanhf(a0.w + bb);
    biasOut[4 * D_ + jb] = tanhf(a1.x + bb);
    biasOut[5 * D_ + jb] = tanhf(a1.y + bb);
    biasOut[6 * D_ + jb] = tanhf(a1.z + bb);
    biasOut[7 * D_ + jb] = tanhf(a1.w + bb);
  }
}

// ---------- k3: per-channel GEMM.  PRE: global_load_lds from bf16 x, XOR-swizzled LDS.
#define BK 64

template <bool PRE>
__global__ __launch_bounds__(256, 2) void k3_gemm(
    const float* __restrict__ x, const ushort* __restrict__ xbf,
    const ushort* __restrict__ wbf, const float* __restrict__ bias,
    float* __restrict__ out) {
  constexpr int LDKE = PRE ? 64 : 72;
  __shared__ ushort As[128 * LDKE];
  __shared__ ushort Bs[128 * LDKE];

  int bid = blockIdx.x;
  int c = bid & 7;            // channel == XCD: x-slice (3.2MB) + weights L2-resident
  int rem = bid >> 3;
  int mt = rem / 6;
  int nt = rem - mt * 6;      // 6 siblings share the A-tile within one XCD
  int m0 = mt * 128, n0 = nt * 128;

  int t = threadIdx.x;
  int lane = t & 63;
  int w = t >> 6;
  int wr = w >> 1, wc = w & 1;

  const ushort* wsrc = wbf + (size_t)c * WSIZE + (size_t)n0 * K_;

  f32x4 acc[4][4] = {};

  if constexpr (PRE) {
    // ---- staging constants: lane l of wave w fills LDS rows [g*8, g*8+8), g = w*4+j.
    // LDS is written linearly (lane*16B); source address carries the inverse XOR-swizzle
    // (rule 21): LDS(row, e) = G(row, e ^ ((row&7)<<3))  [e in bf16 elements]
    int subrow = lane >> 3;                 // row within 8-row group == row&7
    int pq = (lane & 7) ^ subrow;           // swizzled 16B-part index 0..7
    const ushort* aptr[4];
    const ushort* bptr[4];
#pragma unroll
    for (int j = 0; j < 4; ++j) {
      int g = w * 4 + j;
      int m_l = g * 8 + subrow;
      int m = m0 + m_l;
      int b = m / MPT;
      int hw = m - b * MPT;
      int hp = hw / HP;
      int wp = hw - hp * HP;
      aptr[j] = xbf + (((size_t)(b * CIN + c) * IMG + hp * PS) * IMG + wp * PS)
              + (pq >> 1) * IMG + (pq & 1) * 8;
      bptr[j] = wsrc + (g * 8 + subrow) * K_ + pq * 8;
    }

    for (int ks = 0; ks < 4; ++ks) {
      __syncthreads();
#pragma unroll
      for (int j = 0; j < 4; ++j) {
        int g = w * 4 + j;
        gload16(aptr[j] + ks * (4 * IMG), &As[g * 512]);
        gload16(bptr[j] + ks * BK, &Bs[g * 512]);
      }
      __syncthreads();
#pragma unroll
      for (int kk = 0; kk < BK; kk += 32) {
        bf16x8 af[4], bfr[4];
#pragma unroll
        for (int mi = 0; mi < 4; ++mi) {
          int row = wr * 64 + mi * 16 + (lane & 15);
          af[mi] = *(const bf16x8*)&As[row * 64 +
                     ((kk + (lane >> 4) * 8) ^ ((row & 7) << 3))];
        }
#pragma unroll
        for (int ni = 0; ni < 4; ++ni) {
          int row = wc * 64 + ni * 16 + (lane & 15);
          bfr[ni] = *(const bf16x8*)&Bs[row * 64 +
                      ((kk + (lane >> 4) * 8) ^ ((row & 7) << 3))];
        }
#pragma unroll
        for (int mi = 0; mi < 4; ++mi)
#pragma unroll
          for (int ni = 0; ni < 4; ++ni)
            acc[mi][ni] = __builtin_amdgcn_mfma_f32_16x16x32_bf16(af[mi], bfr[ni], acc[mi][ni], 0, 0, 0);
      }
    }
  } else {
    // ---- fallback: register-staged from fp32 x (round-1 path, padded LDS)
    int m_l = t & 127;
    int pgrp = t >> 7;
    int m = m0 + m_l;
    int b = m / MPT;
    int hw = m - b * MPT;
    int hp = hw / HP;
    int wp = hw - hp * HP;
    const float* xrow0 = x + (((size_t)(b * CIN + c) * IMG + hp * PS) * IMG + wp * PS);

    for (int ks = 0; ks < 4; ++ks) {
      __syncthreads();
#pragma unroll
      for (int s = 0; s < 2; ++s) {
        int pl = s * 2 + pgrp;
        const float* src = xrow0 + (ks * 4 + pl) * IMG;
        float4 f0 = *(const float4*)(src + 0);
        float4 f1 = *(const float4*)(src + 4);
        float4 f2 = *(const float4*)(src + 8);
        float4 f3 = *(const float4*)(src + 12);
        union { ushort u[16]; uint4 v[2]; } pk;
        pk.u[0]  = f2bf(f0.x); pk.u[1]  = f2bf(f0.y); pk.u[2]  = f2bf(f0.z); pk.u[3]  = f2bf(f0.w);
        pk.u[4]  = f2bf(f1.x); pk.u[5]  = f2bf(f1.y); pk.u[6]  = f2bf(f1.z); pk.u[7]  = f2bf(f1.w);
        pk.u[8]  = f2bf(f2.x); pk.u[9]  = f2bf(f2.y); pk.u[10] = f2bf(f2.z); pk.u[11] = f2bf(f2.w);
        pk.u[12] = f2bf(f3.x); pk.u[13] = f2bf(f3.y); pk.u[14] = f2bf(f3.z); pk.u[15] = f2bf(f3.w);
        uint4* dst = (uint4*)&As[m_l * LDKE + pl * 16];
        dst[0] = pk.v[0];
        dst[1] = pk.v[1];
      }
#pragma unroll
      for (int i2 = 0; i2 < 4; ++i2) {
        int cg = t + i2 * 256;
        int n_l = cg >> 3, part = cg & 7;
        *(uint4*)&Bs[n_l * LDKE + part * 8] =
            *(const uint4*)(wsrc + n_l * K_ + ks * BK + part * 8);
      }
      __syncthreads();
#pragma unroll
      for (int kk = 0; kk < BK; kk += 32) {
        bf16x8 af[4], bfr[4];
#pragma unroll
        for (int mi = 0; mi < 4; ++mi)
          af[mi] = *(const bf16x8*)&As[(wr * 64 + mi * 16 + (lane & 15)) * LDKE + kk + (lane >> 4) * 8];
#pragma unroll
        for (int ni = 0; ni < 4; ++ni)
          bfr[ni] = *(const bf16x8*)&Bs[(wc * 64 + ni * 16 + (lane & 15)) * LDKE + kk + (lane >> 4) * 8];
#pragma unroll
        for (int mi = 0; mi < 4; ++mi)
#pragma unroll
          for (int ni = 0; ni < 4; ++ni)
            acc[mi][ni] = __builtin_amdgcn_mfma_f32_16x16x32_bf16(af[mi], bfr[ni], acc[mi][ni], 0, 0, 0);
      }
    }
  }

  // ---- epilogue: + bias.  C/D: col = lane&15, row = (lane>>4)*4 + reg
  int col_l = lane & 15;
  int rowg = lane >> 4;
  float bv[4];
#pragma unroll
  for (int ni = 0; ni < 4; ++ni)
    bv[ni] = bias[c * D_ + n0 + wc * 64 + ni * 16 + col_l];
#pragma unroll
  for (int mi = 0; mi < 4; ++mi) {
#pragma unroll
    for (int r = 0; r < 4; ++r) {
      int mrow = m0 + wr * 64 + mi * 16 + rowg * 4 + r;
      int b2 = mrow / MPT;
      int hw2 = mrow - b2 * MPT;
      float* op = out + ((size_t)b2 * (CIN * MPT) + c * MPT + hw2) * D_ + n0 + wc * 64 + col_l;
#pragma unroll
      for (int ni = 0; ni < 4; ++ni)
        op[ni * 16] = acc[mi][ni][r] + bv[ni];
    }
  }
}

extern "C" void kernel_launch(void* const* d_in, const int* in_sizes, int n_in,
                              void* d_out, int out_size, void* d_ws, size_t ws_size,
                              hipStream_t stream) {
  const float* x  = (const float*)d_in[0];
  const float* ce = (const float*)d_in[2];
  const float* w1 = (const float*)d_in[3];
  const float* b1 = (const float*)d_in[4];
  const float* w2 = (const float*)d_in[5];
  const float* b2 = (const float*)d_in[6];
  float* out = (float*)d_out;

  char* ws = (char*)d_ws;
  float*  ht      = (float*)ws;                    // 128*8*4   = 4096 B  (transposed h)
  float*  biasOut = (float*)(ws + 4096);           // 8*768*4   = 24576 B
  ushort* wbf     = (ushort*)(ws + 4096 + 24576);  // 8*196608*2 = 3145728 B
  ushort* xbf     = (ushort*)(ws + 4096 + 24576 + 3145728);  // XN*2 = 25690112 B
  const size_t NEED = 4096 + 24576 + 3145728 + (size_t)XN * 2;

  bool pre = ws_size >= NEED;
  int nCol = NJ / 256;                 // 771 exactly
  int nConv = pre ? 512 : 0;

  k1_fc1<<<dim3(CIN), dim3(512), 0, stream>>>(ce, w1, b1, ht);
  k2_fused<<<dim3(nCol + nConv), dim3(256), 0, stream>>>(ht, w2, b2, x, wbf, biasOut, xbf, nCol);
  if (pre)
    k3_gemm<true><<<dim3(8 * 49 * 6), dim3(256), 0, stream>>>(x, xbf, wbf, biasOut, out);
  else
    k3_gemm<false><<<dim3(8 * 49 * 6), dim3(256), 0, stream>>>(x, xbf, wbf, biasOut, out);
}